// Round 6
// baseline (1305.209 us; speedup 1.0000x reference)
//
#include <hip/hip_runtime.h>
#include <hip/hip_cooperative_groups.h>

namespace cg = cooperative_groups;

// FeatureSimilarityLoss: E=640000 edges, D=128, NUM_S=50000 (fixed).
// loss = mean over valid s of Σ_{e∈s} w_e ||a_e - mean_s||², mean_s = F_s/(w_s+1e-8)
// Expanded: var_s = S2_s - ||F_s||²·inv·(2 - w_s·inv);  ||F_s||² = Σ_slices ||F_s[slice]||²
//
// R3: bf16 slice-major af_t[4][NA][32], 4 L2-resident slice passes (264->163us).
// R5 post-mortem: all real kernels < 41us; ~half of the 155us is the 11 graph-node
// boundaries (~4us each, measured R4->R5) + per-dispatch drain. This round: single
// cooperative mega-kernel, grid.sync() between phases. Numerics unchanged.

#define D  128
#define NS 50000

__device__ __forceinline__ unsigned bfq(float f) {   // f32 -> bf16 (RNE), low 16 bits
    unsigned u = __float_as_uint(f);
    return (u + 0x7FFFu + ((u >> 16) & 1u)) >> 16;
}

__global__ __launch_bounds__(256, 4) void mega(
    const float* __restrict__ ew,
    const float* __restrict__ af,
    const int* __restrict__ s_idx,
    const int* __restrict__ a_idx,
    int* __restrict__ hist,
    float* __restrict__ accum,        // [0]=var_sum [1]=n_valid
    int* __restrict__ offsets,        // [NS+1]
    int* __restrict__ cursor,
    int* __restrict__ partials,       // [64]
    float* __restrict__ fn2,
    float* __restrict__ s2acc,
    float* __restrict__ wsumv,
    ushort* __restrict__ af_t,        // [4][NA][32] bf16
    unsigned long long* __restrict__ sorted_wa,
    float* __restrict__ out,
    int E, int num_s, int num_a)
{
    cg::grid_group grid = cg::this_grid();
    const int tid      = threadIdx.x;
    const int gtid     = blockIdx.x * 256 + tid;
    const int nthreads = gridDim.x * 256;

    __shared__ int wtot[4];
    __shared__ int sp[64];
    __shared__ int stot_s;
    __shared__ float sv[4], sc[4];

    // ---- phase 0: zero hist/accum + transpose af[NA][128]f32 -> af_t[4][NA][32]bf16 ----
    for (int i = gtid; i < num_s; i += nthreads) hist[i] = 0;
    if (gtid == 0) { accum[0] = 0.f; accum[1] = 0.f; }
    for (int u = gtid; u < num_a * 16; u += nthreads) {
        int a    = u >> 4;
        int comp = (u & 15) << 3;
        const float* src = af + (size_t)a * D + comp;
        float4 v0 = *reinterpret_cast<const float4*>(src);
        float4 v1 = *reinterpret_cast<const float4*>(src + 4);
        int p = comp >> 5, cc = comp & 31;
        uint4 o;
        o.x = (bfq(v0.y) << 16) | bfq(v0.x);
        o.y = (bfq(v0.w) << 16) | bfq(v0.z);
        o.z = (bfq(v1.y) << 16) | bfq(v1.x);
        o.w = (bfq(v1.w) << 16) | bfq(v1.z);
        *reinterpret_cast<uint4*>(af_t + ((size_t)p * num_a + a) * 32 + cc) = o;
    }
    grid.sync();

    // ---- phase 1: histogram of s ----
    for (int i = gtid; i < E; i += nthreads) atomicAdd(&hist[s_idx[i]], 1);
    grid.sync();

    // ---- phase 2a: per-chunk exclusive scan (1024 bins/chunk), block c scans chunk c ----
    const int nb = (num_s + 1023) >> 10;
    if ((int)blockIdx.x < nb) {
        int base = blockIdx.x * 1024 + tid * 4;
        int v0 = 0, v1 = 0, v2 = 0, v3 = 0;
        if (base + 3 < num_s) {
            int4 h = *reinterpret_cast<const int4*>(hist + base);
            v0 = h.x; v1 = h.y; v2 = h.z; v3 = h.w;
        } else {
            if (base + 0 < num_s) v0 = hist[base + 0];
            if (base + 1 < num_s) v1 = hist[base + 1];
            if (base + 2 < num_s) v2 = hist[base + 2];
        }
        int tsum = v0 + v1 + v2 + v3;
        int lane = tid & 63, wv = tid >> 6;
        int incl = tsum;
        #pragma unroll
        for (int d = 1; d < 64; d <<= 1) { int t = __shfl_up(incl, d, 64); if (lane >= d) incl += t; }
        if (lane == 63) wtot[wv] = incl;
        __syncthreads();
        int wexcl = 0;
        #pragma unroll
        for (int k = 0; k < 4; ++k) if (k < wv) wexcl += wtot[k];
        int texcl = wexcl + incl - tsum;
        if (base + 3 < num_s) {
            int4 o = make_int4(texcl, texcl + v0, texcl + v0 + v1, texcl + v0 + v1 + v2);
            *reinterpret_cast<int4*>(offsets + base) = o;
        } else {
            if (base + 0 < num_s) offsets[base + 0] = texcl;
            if (base + 1 < num_s) offsets[base + 1] = texcl + v0;
            if (base + 2 < num_s) offsets[base + 2] = texcl + v0 + v1;
        }
        if (tid == 255) partials[blockIdx.x] = wexcl + incl;
    }
    grid.sync();

    // ---- phase 2b: every block redundantly scans partials; offsets += chunk base; cursor ----
    if (tid < 64) {
        int v = (tid < nb) ? partials[tid] : 0;
        int incl = v;
        #pragma unroll
        for (int d = 1; d < 64; d <<= 1) { int t = __shfl_up(incl, d, 64); if (tid >= d) incl += t; }
        sp[tid] = incl - v;
        if (tid == 63) stot_s = incl;
    }
    __syncthreads();
    for (int i = gtid; i < num_s; i += nthreads) {
        int o = offsets[i] + sp[i >> 10];
        offsets[i] = o;
        cursor[i]  = o;
    }
    if (gtid == 0) offsets[num_s] = stot_s;
    grid.sync();

    // ---- phase 3: scatter (w,a) packed 8B, ordered by s ----
    for (int i = gtid; i < E; i += nthreads) {
        int p = atomicAdd(&cursor[s_idx[i]], 1);
        unsigned long long wa = ((unsigned long long)(unsigned)a_idx[i] << 32)
                              | (unsigned long long)__float_as_uint(ew[i]);
        sorted_wa[p] = wa;
    }
    grid.sync();

    // ---- phase 4: four slice passes; wave64 per s (16 edge slots x 4 lanes x 16B) ----
    const int wid   = gtid >> 6;
    const int nwave = nthreads >> 6;
    const int lane  = tid & 63;
    const int j     = lane >> 2;     // edge slot 0..15
    const int ccq   = lane & 3;      // 16B chunk (8 comps) 0..3
    for (int p = 0; p < 4; ++p) {
        const ushort* afp = af_t + (size_t)p * num_a * 32;
        for (int s = wid; s < num_s; s += nwave) {
            int beg = offsets[s], end = offsets[s + 1];
            float f0=0.f,f1=0.f,f2=0.f,f3=0.f,f4=0.f,f5=0.f,f6=0.f,f7=0.f;
            float s2l = 0.f, wl = 0.f;
            for (int b2 = beg; b2 < end; b2 += 16) {
                int idx = b2 + j;
                unsigned long long wa = 0ULL;
                if (idx < end) wa = __builtin_nontemporal_load(sorted_wa + idx);
                float w = __uint_as_float((unsigned)wa);
                int   a = (int)(wa >> 32);
                uint4 x = *reinterpret_cast<const uint4*>(afp + ((size_t)a << 5) + (ccq << 3));
                float x0 = __uint_as_float(x.x << 16), x1 = __uint_as_float(x.x & 0xFFFF0000u);
                float x2 = __uint_as_float(x.y << 16), x3 = __uint_as_float(x.y & 0xFFFF0000u);
                float x4 = __uint_as_float(x.z << 16), x5 = __uint_as_float(x.z & 0xFFFF0000u);
                float x6 = __uint_as_float(x.w << 16), x7 = __uint_as_float(x.w & 0xFFFF0000u);
                f0 += w * x0; f1 += w * x1; f2 += w * x2; f3 += w * x3;
                f4 += w * x4; f5 += w * x5; f6 += w * x6; f7 += w * x7;
                s2l += w * (x0*x0 + x1*x1 + x2*x2 + x3*x3 + x4*x4 + x5*x5 + x6*x6 + x7*x7);
                wl  += w;
            }
            // reduce over edge slots j (lane bits 2..5)
            #pragma unroll
            for (int m = 4; m <= 32; m <<= 1) {
                f0 += __shfl_xor(f0, m, 64); f1 += __shfl_xor(f1, m, 64);
                f2 += __shfl_xor(f2, m, 64); f3 += __shfl_xor(f3, m, 64);
                f4 += __shfl_xor(f4, m, 64); f5 += __shfl_xor(f5, m, 64);
                f6 += __shfl_xor(f6, m, 64); f7 += __shfl_xor(f7, m, 64);
                s2l += __shfl_xor(s2l, m, 64);
                wl  += __shfl_xor(wl,  m, 64);
            }
            float n2 = f0*f0 + f1*f1 + f2*f2 + f3*f3 + f4*f4 + f5*f5 + f6*f6 + f7*f7;
            n2  += __shfl_xor(n2, 1, 64);  n2  += __shfl_xor(n2, 2, 64);
            s2l += __shfl_xor(s2l, 1, 64); s2l += __shfl_xor(s2l, 2, 64);
            if (lane == 0) {   // exclusive owner (same wave every pass) -> plain RMW
                if (p == 0) { fn2[s] = n2;  s2acc[s] = s2l;  wsumv[s] = wl; }
                else        { fn2[s] += n2; s2acc[s] += s2l; }
            }
        }
        grid.sync();
    }

    // ---- phase 5: loss reduction + finalize ----
    {
        float lv = 0.f, lc = 0.f;
        for (int s = gtid; s < num_s; s += nthreads) {
            float w = wsumv[s];
            if (w > 0.f) {
                float inv = 1.f / (w + 1e-8f);
                lv += s2acc[s] - fn2[s] * inv * (2.f - w * inv);
                lc += 1.f;
            }
        }
        #pragma unroll
        for (int m = 1; m < 64; m <<= 1) { lv += __shfl_xor(lv, m, 64); lc += __shfl_xor(lc, m, 64); }
        int wv2 = tid >> 6;
        if ((tid & 63) == 0) { sv[wv2] = lv; sc[wv2] = lc; }
        __syncthreads();
        if (tid == 0) {
            atomicAdd(accum + 0, sv[0] + sv[1] + sv[2] + sv[3]);
            atomicAdd(accum + 1, sc[0] + sc[1] + sc[2] + sc[3]);
        }
    }
    grid.sync();
    if (gtid == 0) {
        float c = accum[1];
        out[0] = (c > 0.f) ? (accum[0] / fmaxf(c, 1.f)) : 0.f;
    }
}

extern "C" void kernel_launch(void* const* d_in, const int* in_sizes, int n_in,
                              void* d_out, int out_size, void* d_ws, size_t ws_size,
                              hipStream_t stream) {
    const float* ew = (const float*)d_in[0];          // [E]
    const float* af = (const float*)d_in[1];          // [NA, 128]
    const int*   ei = (const int*)d_in[2];            // [2, E] flat int32
    int E     = in_sizes[0];
    int num_a = in_sizes[1] / D;
    int num_s = NS;

    const int* s_idx = ei;
    const int* a_idx = ei + E;

    // workspace carve-out (~19.1MB)
    char* ws = (char*)d_ws;
    size_t off = 0;
    auto alloc = [&](size_t bytes) -> char* {
        off = (off + 15) & ~(size_t)15;
        char* p = ws + off;
        off += bytes;
        return p;
    };
    int*   hist     = (int*)alloc((size_t)(num_s + 2) * 4);
    float* accum    = (float*)(hist + num_s);
    int*   offsets  = (int*)alloc((size_t)(num_s + 1) * 4);
    int*   cursor   = (int*)alloc((size_t)num_s * 4);
    int*   partials = (int*)alloc(64 * 4);
    float* fn2      = (float*)alloc((size_t)num_s * 4);
    float* s2acc    = (float*)alloc((size_t)num_s * 4);
    float* wsumv    = (float*)alloc((size_t)num_s * 4);
    ushort* af_t    = (ushort*)alloc((size_t)4 * num_a * 32 * 2);          // 12.8MB
    unsigned long long* sorted_wa = (unsigned long long*)alloc((size_t)E * 8); // 5.1MB

    float* outp = (float*)d_out;

    // co-residency-safe grid for cooperative launch
    int occ = 0;
    hipOccupancyMaxActiveBlocksPerMultiprocessor(&occ, (const void*)mega, 256, 0);
    if (occ < 1) occ = 1;
    int grid = occ * 256;            // 256 CUs on gfx950
    if (grid > 1024) grid = 1024;
    if (grid < 64) grid = 64;        // still >= nb chunks (49)

    void* args[] = { (void*)&ew, (void*)&af, (void*)&s_idx, (void*)&a_idx,
                     (void*)&hist, (void*)&accum, (void*)&offsets, (void*)&cursor,
                     (void*)&partials, (void*)&fn2, (void*)&s2acc, (void*)&wsumv,
                     (void*)&af_t, (void*)&sorted_wa, (void*)&outp,
                     (void*)&E, (void*)&num_s, (void*)&num_a };
    hipLaunchCooperativeKernel((const void*)mega, dim3(grid), dim3(256), args, 0, stream);
}

// Round 7
// 194.396 us; speedup vs baseline: 6.7142x; 6.7142x over previous
//
#include <hip/hip_runtime.h>

// FeatureSimilarityLoss: E=640000 edges, D=128, NUM_S=50000 (fixed).
// loss = mean over valid s of Σ_{e∈s} w_e ||a_e - mean_s||², mean_s = F_s/(w_s+1e-8)
// Expanded: var_s = S2_s - ||F_s||²·inv·(2 - w_s·inv);  ||F_s||² = Σ_slices ||F_s[slice]||²
//
// R3: bf16 slice-major af_t[4][NA][32]; L2-resident slice passes (264->163us).
// R6 post-mortem: cooperative grid.sync() costs ~120us/sync on MI355X (cross-XCD
//   fence) -> mega-kernel 1340us. REVERTED to multi-dispatch.
// R7: (a) 4 slice passes -> ONE dispatch, slice chosen by XCD (blockIdx&7)>>1 so
//   each XCD L2 holds one 3.2MB slice; per-(slice,s) exclusive writer, no atomics.
//   (b) loss+finalize fused via last-block done-counter (device-scope atomics).

#define D  128
#define NS 50000

typedef unsigned long long ull;

__device__ __forceinline__ unsigned bfq(float f) {   // f32 -> bf16 (RNE), low 16 bits
    unsigned u = __float_as_uint(f);
    return (u + 0x7FFFu + ((u >> 16) & 1u)) >> 16;
}

// ---------- A: zero hist/accum/done + transpose af[NA][128]f32 -> af_t[4][NA][32]bf16 ----------

__global__ void zero_transpose(const float* __restrict__ af, ushort* __restrict__ af_t,
                               int* __restrict__ zero_base, int num_a, int nzero) {
    int gtid = blockIdx.x * 256 + threadIdx.x;
    for (int i = gtid; i < nzero; i += gridDim.x * 256) zero_base[i] = 0;

    for (int u = gtid; u < num_a * 16; u += gridDim.x * 256) {
        int a    = u >> 4;
        int comp = (u & 15) << 3;
        const float* src = af + (size_t)a * D + comp;
        float4 v0 = *reinterpret_cast<const float4*>(src);
        float4 v1 = *reinterpret_cast<const float4*>(src + 4);
        int p = comp >> 5, cc = comp & 31;
        uint4 o;
        o.x = (bfq(v0.y) << 16) | bfq(v0.x);
        o.y = (bfq(v0.w) << 16) | bfq(v0.z);
        o.z = (bfq(v1.y) << 16) | bfq(v1.x);
        o.w = (bfq(v1.w) << 16) | bfq(v1.z);
        *reinterpret_cast<uint4*>(af_t + ((size_t)p * num_a + a) * 32 + cc) = o;
    }
}

// ---------- B: histogram ----------

__global__ void hist_kernel(const int* __restrict__ s_idx, int* __restrict__ hist, int E) {
    int i = blockIdx.x * blockDim.x + threadIdx.x;
    if (i < E) atomicAdd(&hist[s_idx[i]], 1);
}

// ---------- C: per-chunk scan (1024 bins/block, 4/thread) ----------

__global__ void scan_blocks(const int* __restrict__ hist,
                            int* __restrict__ offsets,
                            int* __restrict__ partials,
                            int num_s) {
    __shared__ int wtot[4];
    int tid  = threadIdx.x;
    int base = blockIdx.x * 1024 + tid * 4;
    int v0 = 0, v1 = 0, v2 = 0, v3 = 0;
    if (base + 3 < num_s) {
        int4 h = *reinterpret_cast<const int4*>(hist + base);
        v0 = h.x; v1 = h.y; v2 = h.z; v3 = h.w;
    } else {
        if (base + 0 < num_s) v0 = hist[base + 0];
        if (base + 1 < num_s) v1 = hist[base + 1];
        if (base + 2 < num_s) v2 = hist[base + 2];
    }
    int tsum = v0 + v1 + v2 + v3;
    int lane = tid & 63, wv = tid >> 6;
    int incl = tsum;
    #pragma unroll
    for (int d = 1; d < 64; d <<= 1) { int t = __shfl_up(incl, d, 64); if (lane >= d) incl += t; }
    if (lane == 63) wtot[wv] = incl;
    __syncthreads();
    int wexcl = 0;
    #pragma unroll
    for (int k = 0; k < 4; ++k) if (k < wv) wexcl += wtot[k];
    int texcl = wexcl + incl - tsum;
    if (base + 3 < num_s) {
        int4 o = make_int4(texcl, texcl + v0, texcl + v0 + v1, texcl + v0 + v1 + v2);
        *reinterpret_cast<int4*>(offsets + base) = o;
    } else {
        if (base + 0 < num_s) offsets[base + 0] = texcl;
        if (base + 1 < num_s) offsets[base + 1] = texcl + v0;
        if (base + 2 < num_s) offsets[base + 2] = texcl + v0 + v1;
    }
    if (tid == 255) partials[blockIdx.x] = wexcl + incl;
}

// ---------- D: redundant partial-scan per block; offsets += chunk base; init cursor ----------

__global__ void add_offsets(int* __restrict__ offsets, int* __restrict__ cursor,
                            const int* __restrict__ partials, int num_s, int nb) {
    __shared__ int sp[64];
    __shared__ int stot;
    if (threadIdx.x < 64) {
        int lane = threadIdx.x;
        int v    = (lane < nb) ? partials[lane] : 0;
        int incl = v;
        #pragma unroll
        for (int d = 1; d < 64; d <<= 1) { int t = __shfl_up(incl, d, 64); if (lane >= d) incl += t; }
        sp[lane] = incl - v;
        if (lane == 63) stot = incl;
    }
    __syncthreads();
    int i = blockIdx.x * blockDim.x + threadIdx.x;
    if (i < num_s) {
        int o = offsets[i] + sp[i >> 10];
        offsets[i] = o;
        cursor[i]  = o;
    }
    if (i == 0) offsets[num_s] = stot;
}

// ---------- E: scatter (w,a) packed 8B, ordered by s ----------

__global__ void scatter_kernel(const int* __restrict__ s_idx,
                               const int* __restrict__ a_idx,
                               const float* __restrict__ ew,
                               int* __restrict__ cursor,
                               ull* __restrict__ sorted_wa, int E) {
    int i = blockIdx.x * blockDim.x + threadIdx.x;
    if (i < E) {
        int p = atomicAdd(&cursor[s_idx[i]], 1);
        ull wa = ((ull)(unsigned)a_idx[i] << 32) | (ull)__float_as_uint(ew[i]);
        sorted_wa[p] = wa;
    }
}

// ---------- F: all 4 slices in ONE dispatch, slice pinned per XCD ----------
// blockIdx&7 = XCD (round-robin dispatch heuristic); slice p = xcd>>1, s-half h = xcd&1.
// Each XCD's 4MB L2 holds one 3.2MB bf16 slice. Each (p,s) has exactly one owner wave.

__global__ __launch_bounds__(256) void slice_all(
    const ushort* __restrict__ af_t,
    const ull* __restrict__ sorted_wa,
    const int* __restrict__ offsets,
    float* __restrict__ fn2p,        // [4][NS]
    float* __restrict__ s2p,         // [4][NS]
    float* __restrict__ wsumv,       // [NS]
    int num_s, int num_a)
{
    const int xcd  = blockIdx.x & 7;
    const int p    = xcd >> 1;
    const int h    = xcd & 1;
    const int lblk = blockIdx.x >> 3;
    const int nw   = (gridDim.x >> 3) * 4;            // waves per (p,h) group
    const int wid  = lblk * 4 + (threadIdx.x >> 6);
    const int half = (num_s + 1) >> 1;
    const int sbeg = h * half;
    const int send = min(num_s, sbeg + half);
    const int lane = threadIdx.x & 63;
    const int j    = lane >> 2;       // edge slot 0..15
    const int ccq  = lane & 3;        // 16B chunk (8 comps)

    const ushort* afp = af_t + (size_t)p * num_a * 32;
    float* fn2o = fn2p + (size_t)p * num_s;
    float* s2o  = s2p  + (size_t)p * num_s;

    for (int s = sbeg + wid; s < send; s += nw) {
        int beg = offsets[s], end = offsets[s + 1];
        float f0=0.f,f1=0.f,f2=0.f,f3=0.f,f4=0.f,f5=0.f,f6=0.f,f7=0.f;
        float s2l = 0.f, wl = 0.f;
        for (int b2 = beg; b2 < end; b2 += 16) {
            int idx = b2 + j;
            ull wa = 0ULL;
            if (idx < end) wa = __builtin_nontemporal_load(sorted_wa + idx);
            float w = __uint_as_float((unsigned)wa);
            int   a = (int)(wa >> 32);
            uint4 x = *reinterpret_cast<const uint4*>(afp + ((size_t)a << 5) + (ccq << 3));
            float x0 = __uint_as_float(x.x << 16), x1 = __uint_as_float(x.x & 0xFFFF0000u);
            float x2 = __uint_as_float(x.y << 16), x3 = __uint_as_float(x.y & 0xFFFF0000u);
            float x4 = __uint_as_float(x.z << 16), x5 = __uint_as_float(x.z & 0xFFFF0000u);
            float x6 = __uint_as_float(x.w << 16), x7 = __uint_as_float(x.w & 0xFFFF0000u);
            f0 += w * x0; f1 += w * x1; f2 += w * x2; f3 += w * x3;
            f4 += w * x4; f5 += w * x5; f6 += w * x6; f7 += w * x7;
            s2l += w * (x0*x0 + x1*x1 + x2*x2 + x3*x3 + x4*x4 + x5*x5 + x6*x6 + x7*x7);
            wl  += w;
        }
        // reduce over edge slots j (lane bits 2..5)
        #pragma unroll
        for (int m = 4; m <= 32; m <<= 1) {
            f0 += __shfl_xor(f0, m, 64); f1 += __shfl_xor(f1, m, 64);
            f2 += __shfl_xor(f2, m, 64); f3 += __shfl_xor(f3, m, 64);
            f4 += __shfl_xor(f4, m, 64); f5 += __shfl_xor(f5, m, 64);
            f6 += __shfl_xor(f6, m, 64); f7 += __shfl_xor(f7, m, 64);
            s2l += __shfl_xor(s2l, m, 64);
            wl  += __shfl_xor(wl,  m, 64);
        }
        float n2 = f0*f0 + f1*f1 + f2*f2 + f3*f3 + f4*f4 + f5*f5 + f6*f6 + f7*f7;
        n2  += __shfl_xor(n2, 1, 64);  n2  += __shfl_xor(n2, 2, 64);
        s2l += __shfl_xor(s2l, 1, 64); s2l += __shfl_xor(s2l, 2, 64);
        if (lane == 0) {
            fn2o[s] = n2;
            s2o[s]  = s2l;
            if (p == 0) wsumv[s] = wl;
        }
    }
}

// ---------- G: loss reduction + last-block finalize ----------

__global__ void loss_finalize(const float* __restrict__ fn2p, const float* __restrict__ s2p,
                              const float* __restrict__ wsumv,
                              float* __restrict__ accum, int* __restrict__ done,
                              float* __restrict__ out, int num_s) {
    __shared__ float sv[4], sc[4];
    float lv = 0.f, lc = 0.f;
    for (int s = blockIdx.x * blockDim.x + threadIdx.x; s < num_s; s += gridDim.x * blockDim.x) {
        float w = wsumv[s];
        if (w > 0.f) {
            float n2 = fn2p[s] + fn2p[num_s + s] + fn2p[2 * num_s + s] + fn2p[3 * num_s + s];
            float s2 = s2p[s]  + s2p[num_s + s]  + s2p[2 * num_s + s]  + s2p[3 * num_s + s];
            float inv = 1.f / (w + 1e-8f);
            lv += s2 - n2 * inv * (2.f - w * inv);
            lc += 1.f;
        }
    }
    #pragma unroll
    for (int m = 1; m < 64; m <<= 1) { lv += __shfl_xor(lv, m, 64); lc += __shfl_xor(lc, m, 64); }
    int wv = threadIdx.x >> 6;
    if ((threadIdx.x & 63) == 0) { sv[wv] = lv; sc[wv] = lc; }
    __syncthreads();
    if (threadIdx.x == 0) {
        atomicAdd(accum + 0, sv[0] + sv[1] + sv[2] + sv[3]);
        atomicAdd(accum + 1, sc[0] + sc[1] + sc[2] + sc[3]);
        __threadfence();
        unsigned t = atomicAdd((unsigned*)done, 1u);
        if (t == gridDim.x - 1) {
            // device-scope RMW reads: safe across non-coherent per-XCD L2s
            float v = atomicAdd(accum + 0, 0.f);
            float c = atomicAdd(accum + 1, 0.f);
            out[0] = (c > 0.f) ? (v / fmaxf(c, 1.f)) : 0.f;
        }
    }
}

extern "C" void kernel_launch(void* const* d_in, const int* in_sizes, int n_in,
                              void* d_out, int out_size, void* d_ws, size_t ws_size,
                              hipStream_t stream) {
    const float* ew = (const float*)d_in[0];          // [E]
    const float* af = (const float*)d_in[1];          // [NA, 128]
    const int*   ei = (const int*)d_in[2];            // [2, E] flat int32
    const int E     = in_sizes[0];
    const int num_a = in_sizes[1] / D;
    const int num_s = NS;

    const int* s_idx = ei;
    const int* a_idx = ei + E;

    // workspace carve-out (~20.7MB)
    char* ws = (char*)d_ws;
    size_t off = 0;
    auto alloc = [&](size_t bytes) -> char* {
        off = (off + 15) & ~(size_t)15;
        char* p = ws + off;
        off += bytes;
        return p;
    };
    int*   hist     = (int*)alloc((size_t)(num_s + 4) * 4);  // hist[NS] | accum[2] | done | pad
    float* accum    = (float*)(hist + num_s);
    int*   done     = (int*)(hist + num_s + 2);
    int*   offsets  = (int*)alloc((size_t)(num_s + 1) * 4);
    int*   cursor   = (int*)alloc((size_t)num_s * 4);
    int*   partials = (int*)alloc(64 * 4);
    float* fn2p     = (float*)alloc((size_t)4 * num_s * 4);  // [4][NS]
    float* s2p      = (float*)alloc((size_t)4 * num_s * 4);  // [4][NS]
    float* wsumv    = (float*)alloc((size_t)num_s * 4);
    ushort* af_t    = (ushort*)alloc((size_t)4 * num_a * 32 * 2);   // 12.8MB
    ull*   sorted_wa = (ull*)alloc((size_t)E * 8);                  // 5.1MB

    int blocksE = (E + 255) / 256;
    int nb      = (num_s + 1023) / 1024;   // 49

    zero_transpose<<<(num_a * 16 + 255) / 256, 256, 0, stream>>>(af, af_t, hist, num_a, num_s + 4);
    hist_kernel<<<blocksE, 256, 0, stream>>>(s_idx, hist, E);
    scan_blocks<<<nb, 256, 0, stream>>>(hist, offsets, partials, num_s);
    add_offsets<<<(num_s + 255) / 256, 256, 0, stream>>>(offsets, cursor, partials, num_s, nb);
    scatter_kernel<<<blocksE, 256, 0, stream>>>(s_idx, a_idx, ew, cursor, sorted_wa, E);
    slice_all<<<2048, 256, 0, stream>>>(af_t, sorted_wa, offsets, fn2p, s2p, wsumv, num_s, num_a);
    loss_finalize<<<128, 256, 0, stream>>>(fn2p, s2p, wsumv, accum, done, (float*)d_out, num_s);
}

// Round 8
// 152.139 us; speedup vs baseline: 8.5791x; 1.2778x over previous
//
#include <hip/hip_runtime.h>

// FeatureSimilarityLoss: E=640000 edges, D=128, NUM_S=50000 (fixed).
// loss = mean over valid s of Σ_{e∈s} w_e ||a_e - mean_s||², mean_s = F_s/(w_s+1e-8)
// Expanded: var_s = S2_s - ||F_s||²·inv·(2 - w_s·inv);  ||F_s||² = Σ_slices ||F_s[slice]||²
// S2_s = Σ_e w_e·sqnorm[a_e],  sqnorm precomputed once per agent.
//
// Journal: R1 f32 atomics (1136us) -> R2 counting sort + reg accum (307) ->
// R3 4-deep MLP (264) -> R4 bf16 slice-major af_t[4][NA][32], L2-resident passes
// (163) -> R5 fused zero, fewer nodes (155) -> R6 grid.sync REJECTED (1340;
// ~120us/sync cross-XCD) -> R7 XCD-pinned single pass REJECTED (194; latency-
// bound, lost wave parallelism). R8: R5 skeleton + sqnorm hoist + offsets
// pipeline + fused finalize.

#define D  128
#define NS 50000

typedef unsigned long long ull;

__device__ __forceinline__ unsigned bfq(float f) {   // f32 -> bf16 (RNE), low 16 bits
    unsigned u = __float_as_uint(f);
    return (u + 0x7FFFu + ((u >> 16) & 1u)) >> 16;
}

// ---------- A: zero ws heads + transpose af -> bf16 slices + sqnorm ----------
// u = a*16 + c16 (c16 = 8-comp chunk). Wave = 4 agents x 16 chunks; xor-reduce
// bits 0..3 gives per-agent sum of squares. Grid-stride keeps lane alignment
// (stride multiple of 64).

__global__ void prep_kernel(const float* __restrict__ af, ushort* __restrict__ af_t,
                            float* __restrict__ sqnorm, int* __restrict__ zero_base,
                            int num_a, int nzero) {
    int gtid   = blockIdx.x * 256 + threadIdx.x;
    int stride = gridDim.x * 256;
    for (int i = gtid; i < nzero; i += stride) zero_base[i] = 0;

    for (int u = gtid; u < num_a * 16; u += stride) {
        int a    = u >> 4;
        int comp = (u & 15) << 3;
        const float* src = af + (size_t)a * D + comp;
        float4 v0 = *reinterpret_cast<const float4*>(src);
        float4 v1 = *reinterpret_cast<const float4*>(src + 4);
        int p = comp >> 5, cc = comp & 31;
        uint4 o;
        o.x = (bfq(v0.y) << 16) | bfq(v0.x);
        o.y = (bfq(v0.w) << 16) | bfq(v0.z);
        o.z = (bfq(v1.y) << 16) | bfq(v1.x);
        o.w = (bfq(v1.w) << 16) | bfq(v1.z);
        *reinterpret_cast<uint4*>(af_t + ((size_t)p * num_a + a) * 32 + cc) = o;

        // sum of squares of the bf16-rounded values (consistent with fn2 path)
        float q0 = __uint_as_float(o.x << 16), q1 = __uint_as_float(o.x & 0xFFFF0000u);
        float q2 = __uint_as_float(o.y << 16), q3 = __uint_as_float(o.y & 0xFFFF0000u);
        float q4 = __uint_as_float(o.z << 16), q5 = __uint_as_float(o.z & 0xFFFF0000u);
        float q6 = __uint_as_float(o.w << 16), q7 = __uint_as_float(o.w & 0xFFFF0000u);
        float ss = q0*q0 + q1*q1 + q2*q2 + q3*q3 + q4*q4 + q5*q5 + q6*q6 + q7*q7;
        #pragma unroll
        for (int m = 1; m <= 8; m <<= 1) ss += __shfl_xor(ss, m, 64);
        if ((u & 15) == 0) sqnorm[a] = ss;
    }
}

// ---------- B: histogram ----------

__global__ void hist_kernel(const int* __restrict__ s_idx, int* __restrict__ hist, int E) {
    int i = blockIdx.x * blockDim.x + threadIdx.x;
    if (i < E) atomicAdd(&hist[s_idx[i]], 1);
}

// ---------- C: per-chunk scan (1024 bins/block, 4/thread) ----------

__global__ void scan_blocks(const int* __restrict__ hist,
                            int* __restrict__ offsets,
                            int* __restrict__ partials,
                            int num_s) {
    __shared__ int wtot[4];
    int tid  = threadIdx.x;
    int base = blockIdx.x * 1024 + tid * 4;
    int v0 = 0, v1 = 0, v2 = 0, v3 = 0;
    if (base + 3 < num_s) {
        int4 h = *reinterpret_cast<const int4*>(hist + base);
        v0 = h.x; v1 = h.y; v2 = h.z; v3 = h.w;
    } else {
        if (base + 0 < num_s) v0 = hist[base + 0];
        if (base + 1 < num_s) v1 = hist[base + 1];
        if (base + 2 < num_s) v2 = hist[base + 2];
    }
    int tsum = v0 + v1 + v2 + v3;
    int lane = tid & 63, wv = tid >> 6;
    int incl = tsum;
    #pragma unroll
    for (int d = 1; d < 64; d <<= 1) { int t = __shfl_up(incl, d, 64); if (lane >= d) incl += t; }
    if (lane == 63) wtot[wv] = incl;
    __syncthreads();
    int wexcl = 0;
    #pragma unroll
    for (int k = 0; k < 4; ++k) if (k < wv) wexcl += wtot[k];
    int texcl = wexcl + incl - tsum;
    if (base + 3 < num_s) {
        int4 o = make_int4(texcl, texcl + v0, texcl + v0 + v1, texcl + v0 + v1 + v2);
        *reinterpret_cast<int4*>(offsets + base) = o;
    } else {
        if (base + 0 < num_s) offsets[base + 0] = texcl;
        if (base + 1 < num_s) offsets[base + 1] = texcl + v0;
        if (base + 2 < num_s) offsets[base + 2] = texcl + v0 + v1;
    }
    if (tid == 255) partials[blockIdx.x] = wexcl + incl;
}

// ---------- D: redundant partial-scan per block; offsets += chunk base; init cursor ----------

__global__ void add_offsets(int* __restrict__ offsets, int* __restrict__ cursor,
                            const int* __restrict__ partials, int num_s, int nb) {
    __shared__ int sp[64];
    __shared__ int stot;
    if (threadIdx.x < 64) {
        int lane = threadIdx.x;
        int v    = (lane < nb) ? partials[lane] : 0;
        int incl = v;
        #pragma unroll
        for (int d = 1; d < 64; d <<= 1) { int t = __shfl_up(incl, d, 64); if (lane >= d) incl += t; }
        sp[lane] = incl - v;
        if (lane == 63) stot = incl;
    }
    __syncthreads();
    int i = blockIdx.x * blockDim.x + threadIdx.x;
    if (i < num_s) {
        int o = offsets[i] + sp[i >> 10];
        offsets[i] = o;
        cursor[i]  = o;
    }
    if (i == 0) offsets[num_s] = stot;
}

// ---------- E: scatter (w,a) packed 8B, ordered by s ----------

__global__ void scatter_kernel(const int* __restrict__ s_idx,
                               const int* __restrict__ a_idx,
                               const float* __restrict__ ew,
                               int* __restrict__ cursor,
                               ull* __restrict__ sorted_wa, int E) {
    int i = blockIdx.x * blockDim.x + threadIdx.x;
    if (i < E) {
        int p = atomicAdd(&cursor[s_idx[i]], 1);
        ull wa = ((ull)(unsigned)a_idx[i] << 32) | (ull)__float_as_uint(ew[i]);
        sorted_wa[p] = wa;
    }
}

// ---------- F: slice pass (full machine). 32-group per s, 8 slots x 4 chunks. ----------
// P0: also accumulate S2 (via sqnorm gather) and wsum. Offsets for the next s
// are issued before processing the current s (1-deep pipeline).

template<int P0>
__global__ __launch_bounds__(256) void slice_pass(
    const ushort* __restrict__ afp,       // slice base [num_a][32] bf16
    const float* __restrict__ sqnorm,
    const ull* __restrict__ sorted_wa,
    const int* __restrict__ offsets,
    float* __restrict__ fn2, float* __restrict__ s2acc, float* __restrict__ wsumv,
    int num_s)
{
    int gid    = blockIdx.x * 256 + threadIdx.x;
    int group  = gid >> 5;
    int lane   = threadIdx.x & 31;
    int j      = lane >> 2;       // edge slot 0..7
    int ccq    = lane & 3;        // 16B chunk (8 comps)
    int stride = (gridDim.x * 256) >> 5;

    int sc = group;
    if (sc >= num_s) return;
    int bc = offsets[sc], ec = offsets[sc + 1];

    for (;;) {
        int  sn = sc + stride;
        bool have_n = (sn < num_s);
        int  bn = 0, en = 0;
        if (have_n) { bn = offsets[sn]; en = offsets[sn + 1]; }   // prefetched

        float f0=0.f,f1=0.f,f2=0.f,f3=0.f,f4=0.f,f5=0.f,f6=0.f,f7=0.f;
        float s2l = 0.f, wl = 0.f;
        for (int base = bc; base < ec; base += 8) {
            int idx = base + j;
            ull wa = 0ULL;
            if (idx < ec) wa = __builtin_nontemporal_load(sorted_wa + idx);
            float w = __uint_as_float((unsigned)wa);
            int   a = (int)(wa >> 32);
            uint4 x = *reinterpret_cast<const uint4*>(afp + ((size_t)a << 5) + (ccq << 3));
            float x0 = __uint_as_float(x.x << 16), x1 = __uint_as_float(x.x & 0xFFFF0000u);
            float x2 = __uint_as_float(x.y << 16), x3 = __uint_as_float(x.y & 0xFFFF0000u);
            float x4 = __uint_as_float(x.z << 16), x5 = __uint_as_float(x.z & 0xFFFF0000u);
            float x6 = __uint_as_float(x.w << 16), x7 = __uint_as_float(x.w & 0xFFFF0000u);
            f0 += w * x0; f1 += w * x1; f2 += w * x2; f3 += w * x3;
            f4 += w * x4; f5 += w * x5; f6 += w * x6; f7 += w * x7;
            if (P0) {
                if (ccq == 0) {               // one lane per edge slot
                    s2l += w * sqnorm[a];     // full-D S2 contribution
                    wl  += w;
                }
            }
        }
        // reduce over edge slots j (lane bits 2..4)
        #pragma unroll
        for (int m = 4; m <= 16; m <<= 1) {
            f0 += __shfl_xor(f0, m, 64); f1 += __shfl_xor(f1, m, 64);
            f2 += __shfl_xor(f2, m, 64); f3 += __shfl_xor(f3, m, 64);
            f4 += __shfl_xor(f4, m, 64); f5 += __shfl_xor(f5, m, 64);
            f6 += __shfl_xor(f6, m, 64); f7 += __shfl_xor(f7, m, 64);
            if (P0) { s2l += __shfl_xor(s2l, m, 64); wl += __shfl_xor(wl, m, 64); }
        }
        float n2 = f0*f0 + f1*f1 + f2*f2 + f3*f3 + f4*f4 + f5*f5 + f6*f6 + f7*f7;
        n2 += __shfl_xor(n2, 1, 64);
        n2 += __shfl_xor(n2, 2, 64);
        if (lane == 0) {   // exclusive owner of s in this pass
            if (P0) { fn2[sc] = n2;  s2acc[sc] = s2l;  wsumv[sc] = wl; }
            else    { fn2[sc] += n2; }
        }
        if (!have_n) break;
        sc = sn; bc = bn; ec = en;
    }
}

// ---------- G: loss reduction + last-block finalize ----------

__global__ void loss_finalize(const float* __restrict__ fn2, const float* __restrict__ s2acc,
                              const float* __restrict__ wsumv,
                              float* __restrict__ accum, int* __restrict__ done,
                              float* __restrict__ out, int num_s) {
    __shared__ float sv[4], sc[4];
    float lv = 0.f, lc = 0.f;
    for (int s = blockIdx.x * blockDim.x + threadIdx.x; s < num_s; s += gridDim.x * blockDim.x) {
        float w = wsumv[s];
        if (w > 0.f) {
            float inv = 1.f / (w + 1e-8f);
            lv += s2acc[s] - fn2[s] * inv * (2.f - w * inv);
            lc += 1.f;
        }
    }
    #pragma unroll
    for (int m = 1; m < 64; m <<= 1) { lv += __shfl_xor(lv, m, 64); lc += __shfl_xor(lc, m, 64); }
    int wv = threadIdx.x >> 6;
    if ((threadIdx.x & 63) == 0) { sv[wv] = lv; sc[wv] = lc; }
    __syncthreads();
    if (threadIdx.x == 0) {
        atomicAdd(accum + 0, sv[0] + sv[1] + sv[2] + sv[3]);
        atomicAdd(accum + 1, sc[0] + sc[1] + sc[2] + sc[3]);
        __threadfence();
        unsigned t = atomicAdd((unsigned*)done, 1u);
        if (t == gridDim.x - 1) {
            float v = atomicAdd(accum + 0, 0.f);   // device-scope RMW read
            float c = atomicAdd(accum + 1, 0.f);
            out[0] = (c > 0.f) ? (v / fmaxf(c, 1.f)) : 0.f;
        }
    }
}

extern "C" void kernel_launch(void* const* d_in, const int* in_sizes, int n_in,
                              void* d_out, int out_size, void* d_ws, size_t ws_size,
                              hipStream_t stream) {
    const float* ew = (const float*)d_in[0];          // [E]
    const float* af = (const float*)d_in[1];          // [NA, 128]
    const int*   ei = (const int*)d_in[2];            // [2, E] flat int32
    const int E     = in_sizes[0];
    const int num_a = in_sizes[1] / D;
    const int num_s = NS;

    const int* s_idx = ei;
    const int* a_idx = ei + E;

    // workspace carve-out (~19.5MB)
    char* ws = (char*)d_ws;
    size_t off = 0;
    auto alloc = [&](size_t bytes) -> char* {
        off = (off + 15) & ~(size_t)15;
        char* p = ws + off;
        off += bytes;
        return p;
    };
    int*   hist     = (int*)alloc((size_t)(num_s + 4) * 4);  // hist[NS] | accum[2] | done | pad
    float* accum    = (float*)(hist + num_s);
    int*   done     = (int*)(hist + num_s + 2);
    int*   offsets  = (int*)alloc((size_t)(num_s + 1) * 4);
    int*   cursor   = (int*)alloc((size_t)num_s * 4);
    int*   partials = (int*)alloc(64 * 4);
    float* fn2      = (float*)alloc((size_t)num_s * 4);
    float* s2acc    = (float*)alloc((size_t)num_s * 4);
    float* wsumv    = (float*)alloc((size_t)num_s * 4);
    float* sqnorm   = (float*)alloc((size_t)num_a * 4);
    ushort* af_t    = (ushort*)alloc((size_t)4 * num_a * 32 * 2);   // 12.8MB
    ull*   sorted_wa = (ull*)alloc((size_t)E * 8);                  // 5.1MB

    int blocksE = (E + 255) / 256;
    int nb      = (num_s + 1023) / 1024;   // 49

    prep_kernel<<<(num_a * 16 + 255) / 256, 256, 0, stream>>>(af, af_t, sqnorm, hist, num_a, num_s + 4);
    hist_kernel<<<blocksE, 256, 0, stream>>>(s_idx, hist, E);
    scan_blocks<<<nb, 256, 0, stream>>>(hist, offsets, partials, num_s);
    add_offsets<<<(num_s + 255) / 256, 256, 0, stream>>>(offsets, cursor, partials, num_s, nb);
    scatter_kernel<<<blocksE, 256, 0, stream>>>(s_idx, a_idx, ew, cursor, sorted_wa, E);

    const int SLICE_BLOCKS = 2048;
    slice_pass<1><<<SLICE_BLOCKS, 256, 0, stream>>>(af_t + (size_t)0 * num_a * 32, sqnorm,
                                                    sorted_wa, offsets, fn2, s2acc, wsumv, num_s);
    for (int p = 1; p < 4; ++p)
        slice_pass<0><<<SLICE_BLOCKS, 256, 0, stream>>>(af_t + (size_t)p * num_a * 32, sqnorm,
                                                        sorted_wa, offsets, fn2, s2acc, wsumv, num_s);

    loss_finalize<<<128, 256, 0, stream>>>(fn2, s2acc, wsumv, accum, done, (float*)d_out, num_s);
}